// Round 6
// baseline (361.474 us; speedup 1.0000x reference)
//
#include <hip/hip_runtime.h>

// ---------------- problem constants ----------------
#define B_      8
#define A_      64
#define NPAIR   63
#define NC_     128
#define NF_     2560    // K
#define O2_     196     // 14*14
#define NORB_   14
#define AO_     896
#define NCOLS   588     // valid cols: [H_off 196 | S_off 196 | H_on 196]
#define CSTRIDE 640     // padded col stride of HSoff
#define KSTEPS  80      // NF_/32
#define BM      64
#define BN      640
#define BSTEP_BYTES 40960   // BN*32*2 per K-step

typedef short bf16x8 __attribute__((ext_vector_type(8)));
typedef float f32x4  __attribute__((ext_vector_type(4)));

__device__ __forceinline__ unsigned f2bf(float f) {
    unsigned u = __builtin_bit_cast(unsigned, f);
    return (u + 0x7fffu + ((u >> 16) & 1u)) >> 16;   // RNE
}

// ---------------- kernel 1: fused {pack weights | energy head} ----------------
// blocks 0..79: pack W -> bf16 [ks][n=640][k=32] linear; blocks 80..87: energy for b.
__global__ __launch_bounds__(512)
void prep_energy(const float* __restrict__ W_off, const float* __restrict__ W_ovoff,
                 const float* __restrict__ W_on, unsigned short* __restrict__ Bws,
                 const float* __restrict__ x, const float* __restrict__ W1,
                 const float* __restrict__ b1, const float* __restrict__ W2,
                 const float* __restrict__ b2, float* __restrict__ E) {
    const int t = threadIdx.x;
    if (blockIdx.x < KSTEPS) {
        __shared__ float wt[32 * BN];
        const int ks = blockIdx.x;
        for (int e = t; e < 32 * BN; e += 512) {
            int kl = e / BN, c = e - kl * BN;
            int kg = ks * 32 + kl;
            float v = 0.f;
            if (c < O2_)          v = W_off  [(size_t)kg * O2_ + c];
            else if (c < 2 * O2_) v = W_ovoff[(size_t)kg * O2_ + (c - O2_)];
            else if (c < 3 * O2_) v = W_on   [(size_t)kg * O2_ + (c - 2 * O2_)];
            wt[kl * BN + c] = v;
        }
        __syncthreads();
        unsigned short* out = Bws + (size_t)ks * (BN * 32);
        for (int e = t; e < BN * 4; e += 512) {
            int n = e >> 2, sg = e & 3;
            uint4 w;
            w.x = f2bf(wt[(sg * 8 + 0) * BN + n]) | (f2bf(wt[(sg * 8 + 1) * BN + n]) << 16);
            w.y = f2bf(wt[(sg * 8 + 2) * BN + n]) | (f2bf(wt[(sg * 8 + 3) * BN + n]) << 16);
            w.z = f2bf(wt[(sg * 8 + 4) * BN + n]) | (f2bf(wt[(sg * 8 + 5) * BN + n]) << 16);
            w.w = f2bf(wt[(sg * 8 + 6) * BN + n]) | (f2bf(wt[(sg * 8 + 7) * BN + n]) << 16);
            *(uint4*)(out + (size_t)n * 32 + sg * 8) = w;
        }
    } else {
        __shared__ float partial[8];
        const int b = blockIdx.x - KSTEPS;
        const int lane = t & 63;
        const int w = t >> 6;
        float esum = 0.f;
        for (int aa = 0; aa < 8; ++aa) {
            const int a = w * 8 + aa;
            const float* xr = x + (size_t)(b * A_ + a) * NC_;
            float hj = b1[lane];
            for (int k = 0; k < NC_; ++k) hj = fmaf(xr[k], W1[k * 64 + lane], hj);
            float sp = fmaxf(hj, 0.f) + log1pf(expf(-fabsf(hj))) - 0.69314718055994531f;
            float v = sp * W2[lane];
            for (int off = 32; off; off >>= 1) v += __shfl_down(v, off);
            if (lane == 0) esum += v + b2[0];
        }
        if (lane == 0) partial[w] = esum;
        __syncthreads();
        if (t == 0) {
            float e = 0.f;
            for (int k = 0; k < 8; ++k) e += partial[k];
            E[b] = e;
        }
    }
}

// ---------------- kernel 2: MFMA GEMM; BM=64, grid 504 (2 blocks/CU), acc[2][10] ----------------
// 8 waves (2M x 4N), wave-tile 32x160; A via LDS dbuf (XOR-swizzled), B global->reg rolling.
__global__ __launch_bounds__(512, 4)
void gemm_off(const float* __restrict__ V, const unsigned short* __restrict__ Bws,
              const float* __restrict__ b_off, const float* __restrict__ b_ovoff,
              const float* __restrict__ b_on, float* __restrict__ HSoff) {
    __shared__ alignas(16) unsigned short Alds[2][BM * 32];   // 4 KB per buf

    const int tid  = threadIdx.x;
    const int mt   = blockIdx.x;
    const int lane = tid & 63;
    const int wv   = tid >> 6;
    const int wm   = wv >> 2, wn = wv & 3;

    const int arow = tid >> 3, aseg = tid & 7;                // 64 rows x 8 segs of 4 floats
    const float* aptr = V + (size_t)(mt * BM + arow) * NF_ + aseg * 4;

    const char* bp = (const char*)Bws + (size_t)(wn * 160 + (lane & 15)) * 64 + (lane >> 4) * 16;
#define BFRAG(t_, nf_) (*(const bf16x8*)(bp + (size_t)(t_) * BSTEP_BYTES + (nf_) * 1024))

    f32x4 acc[2][10];
#pragma unroll
    for (int mf = 0; mf < 2; ++mf)
#pragma unroll
        for (int nf = 0; nf < 10; ++nf)
            acc[mf][nf] = (f32x4){0.f, 0.f, 0.f, 0.f};

    float4 pv;
    auto loadA = [&](int ks) {
        pv = *(const float4*)(aptr + ks * 32);
    };
    auto writeA = [&](int bf) {
        uint2 w;
        w.x = f2bf(pv.x) | (f2bf(pv.y) << 16);
        w.y = f2bf(pv.z) | (f2bf(pv.w) << 16);
        unsigned byte = ((unsigned)(arow * 64 + aseg * 8)) ^ ((unsigned)(arow & 7) << 4);
        *(uint2*)((char*)&Alds[bf][0] + byte) = w;
    };

    const int ar = wm * 32 + (lane & 15);
    const unsigned kb = (unsigned)(lane >> 4) * 16;

#define ARD(mf_) (*(const bf16x8*)((const char*)Ab + ((((unsigned)((ar + (mf_) * 16) * 64) + kb)) ^ ((unsigned)((ar + (mf_) * 16) & 7) << 4))))

#define MFMA2(bv_, nf_) {                                                                  \
    acc[0][nf_] = __builtin_amdgcn_mfma_f32_16x16x32_bf16(af0, bv_, acc[0][nf_], 0, 0, 0); \
    acc[1][nf_] = __builtin_amdgcn_mfma_f32_16x16x32_bf16(af1, bv_, acc[1][nf_], 0, 0, 0); }

    bf16x8 bq0, bq1, bq2, bq3, bq4;

    // ---- prologue ----
    loadA(0);
    writeA(0);
    bq0 = BFRAG(0, 0); bq1 = BFRAG(0, 1); bq2 = BFRAG(0, 2); bq3 = BFRAG(0, 3); bq4 = BFRAG(0, 4);
    loadA(1);
    asm volatile("s_waitcnt lgkmcnt(0)" ::: "memory");
    __builtin_amdgcn_s_barrier();
    __builtin_amdgcn_sched_barrier(0);

    int cur = 0;
    for (int t = 0; t < KSTEPS; ++t) {
        const unsigned short* Ab = &Alds[cur][0];
        bf16x8 af0 = ARD(0), af1 = ARD(1);

        MFMA2(bq0, 0); bq0 = BFRAG(t, 5);
        MFMA2(bq1, 1); bq1 = BFRAG(t, 6);
        MFMA2(bq2, 2); bq2 = BFRAG(t, 7);
        MFMA2(bq3, 3); bq3 = BFRAG(t, 8);
        MFMA2(bq4, 4); bq4 = BFRAG(t, 9);
        MFMA2(bq0, 5); bq0 = BFRAG(t + 1, 0);     // t=79 reads pad step 80 (never consumed)
        MFMA2(bq1, 6); bq1 = BFRAG(t + 1, 1);
        MFMA2(bq2, 7); bq2 = BFRAG(t + 1, 2);
        MFMA2(bq3, 8); bq3 = BFRAG(t + 1, 3);
        MFMA2(bq4, 9); bq4 = BFRAG(t + 1, 4);

        if (t < KSTEPS - 1) {
            writeA(cur ^ 1);                       // A(t+1) regs -> LDS
            int ks2 = t + 2 < KSTEPS ? t + 2 : KSTEPS - 1;
            loadA(ks2);                            // issue A(t+2)
            asm volatile("s_waitcnt lgkmcnt(0)" ::: "memory");
            __builtin_amdgcn_s_barrier();
            __builtin_amdgcn_sched_barrier(0);
        }
        cur ^= 1;
    }

    // ---- epilogue: C/D layout col=lane&15, row=(lane>>4)*4+reg ----
    const int c16 = lane & 15, rg = lane >> 4;
#pragma unroll
    for (int nf = 0; nf < 10; ++nf) {
        int C = wn * 160 + nf * 16 + c16;
        if (C >= NCOLS) continue;
        float bias = (C < O2_) ? b_off[C] : (C < 2 * O2_) ? b_ovoff[C - O2_] : b_on[C - 2 * O2_];
#pragma unroll
        for (int mf = 0; mf < 2; ++mf) {
            int R = mt * BM + wm * 32 + mf * 16 + rg * 4;
            float* o = HSoff + (size_t)R * CSTRIDE + C;
            o[0]           = acc[mf][nf][0] + bias;
            o[CSTRIDE]     = acc[mf][nf][1] + bias;
            o[2 * CSTRIDE] = acc[mf][nf][2] + bias;
            o[3 * CSTRIDE] = acc[mf][nf][3] + bias;
        }
    }
#undef BFRAG
#undef ARD
#undef MFMA2
}

// ---------------- kernel 3: Hon = rowmean over 63 pair rows of cols [392,588) ----------------
__global__ void hon_reduce(const float* __restrict__ HSoff, float* __restrict__ Hon) {
    const int g = blockIdx.x;       // 0..511
    const int t = threadIdx.x;      // 256, t<196 active
    if (t >= O2_) return;
    const float* p0 = HSoff + (size_t)g * NPAIR * CSTRIDE + 2 * O2_ + t;
    const float* p1 = p0 + (size_t)21 * CSTRIDE;
    const float* p2 = p0 + (size_t)42 * CSTRIDE;
    float a0 = 0.f, a1 = 0.f, a2 = 0.f;
#pragma unroll 3
    for (int j = 0; j < 21; ++j) {
        a0 += p0[0]; a1 += p1[0]; a2 += p2[0];
        p0 += CSTRIDE; p1 += CSTRIDE; p2 += CSTRIDE;
    }
    Hon[(size_t)g * O2_ + t] = (a0 + a1 + a2) * (1.f / (float)NPAIR);
}

// ---------------- kernel 4: assemble H and S, LDS-staged, fully coalesced ----------------
__global__ __launch_bounds__(256)
void assemble_k(const float* __restrict__ HSoff, const float* __restrict__ Hon,
                const int* __restrict__ Z, const float* __restrict__ ov_emb,
                const float* __restrict__ orbE, const float* __restrict__ s0E,
                float* __restrict__ H, float* __restrict__ S) {
    __shared__ float Ai[NPAIR * 197];
    __shared__ float Bj[2][16 * 200];
    __shared__ float Dg[O2_];
    __shared__ float Dd[NORB_];

    const int bid = blockIdx.x;
    const int h = bid & 1, i = (bid >> 1) & 63, b = bid >> 7;
    const int t = threadIdx.x;
    const int g = b * A_ + i;
    const int z = Z[g];
    float* out = (h ? S : H) + (size_t)b * AO_ * AO_;

    const float* abase = HSoff + (size_t)g * NPAIR * CSTRIDE + h * O2_;
    for (int u = t; u < NPAIR * O2_; u += 256) {
        int jj = u / O2_, e = u - jj * O2_;
        Ai[jj * 197 + e] = abase[(size_t)jj * CSTRIDE + e];
    }
    if (t < O2_)   Dg[t] = h ? ov_emb[(size_t)z * O2_ + t]   : Hon[(size_t)g * O2_ + t];
    if (t < NORB_) Dd[t] = h ? s0E[(size_t)z * NORB_ + t]    : orbE[(size_t)z * NORB_ + t];

    auto stageB = [&](int buf, int jc) {
        for (int u = t; u < 16 * O2_; u += 256) {
            int jl = u / O2_, e = u - jl * O2_;
            int j = jc * 16 + jl;
            if (j != i) {
                int idx = (i < j) ? i : i - 1;
                Bj[buf][jl * 200 + e] =
                    HSoff[((size_t)(b * A_ + j) * NPAIR + idx) * CSTRIDE + h * O2_ + e];
            }
        }
    };
    stageB(0, 0);
    __syncthreads();

    const int tj = t / NORB_, tq = t - tj * NORB_;   // valid for t<224
    for (int jc = 0; jc < 4; ++jc) {
        if (jc < 3) stageB((jc + 1) & 1, jc + 1);
        if (t < 224) {
            const int j = jc * 16 + tj;
            const int cur = jc & 1;
#pragma unroll
            for (int p = 0; p < NORB_; ++p) {
                float v;
                if (j == i) {
                    v = 0.5f * (Dg[p * NORB_ + tq] + Dg[tq * NORB_ + p]);
                    if (p == tq) v += Dd[p];
                } else {
                    int jj = (j < i) ? j : j - 1;
                    v = 0.5f * (Ai[jj * 197 + p * NORB_ + tq] + Bj[cur][tj * 200 + tq * NORB_ + p]);
                }
                out[(size_t)(i * NORB_ + p) * AO_ + jc * 224 + t] = v;
            }
        }
        __syncthreads();
    }
}

// ---------------- launcher ----------------
extern "C" void kernel_launch(void* const* d_in, const int* in_sizes, int n_in,
                              void* d_out, int out_size, void* d_ws, size_t ws_size,
                              hipStream_t stream) {
    const int*   Z       = (const int*)  d_in[0];
    const float* x       = (const float*)d_in[2];
    const float* V       = (const float*)d_in[3];
    const float* W_off   = (const float*)d_in[4];
    const float* b_off   = (const float*)d_in[5];
    const float* W_on    = (const float*)d_in[6];
    const float* b_on    = (const float*)d_in[7];
    const float* W_ovoff = (const float*)d_in[8];
    const float* b_ovoff = (const float*)d_in[9];
    const float* ov_emb  = (const float*)d_in[10];
    const float* orbE    = (const float*)d_in[11];
    const float* s0E     = (const float*)d_in[12];
    const float* W1      = (const float*)d_in[13];
    const float* b1      = (const float*)d_in[14];
    const float* W2      = (const float*)d_in[15];
    const float* b2      = (const float*)d_in[16];

    float* H = (float*)d_out;
    float* S = H + (size_t)B_ * AO_ * AO_;
    float* E = S + (size_t)B_ * AO_ * AO_;

    char* ws = (char*)d_ws;
    unsigned short* Bws = (unsigned short*)ws;                     // 81 steps x 40960 B (step 80 = pad)
    float* HSoff = (float*)(ws + (size_t)4  * 1024 * 1024);        // 82,575,360 B
    float* Hon   = (float*)(ws + (size_t)88 * 1024 * 1024);        //    401,408 B

    prep_energy<<<KSTEPS + B_, 512, 0, stream>>>(W_off, W_ovoff, W_on, Bws,
                                                 x, W1, b1, W2, b2, E);
    gemm_off   <<<504,  512, 0, stream>>>(V, Bws, b_off, b_ovoff, b_on, HSoff);
    hon_reduce <<<512,  256, 0, stream>>>(HSoff, Hon);
    assemble_k <<<1024, 256, 0, stream>>>(HSoff, Hon, Z, ov_emb, orbE, s0E, H, S);
}

// Round 7
// 308.540 us; speedup vs baseline: 1.1716x; 1.1716x over previous
//
#include <hip/hip_runtime.h>

// ---------------- problem constants ----------------
#define B_      8
#define A_      64
#define NPAIR   63
#define NC_     128
#define NF_     2560    // K
#define O2_     196     // 14*14
#define NORB_   14
#define AO_     896
#define NCOLS   588     // valid cols: [H_off 196 | S_off 196 | H_on 196]
#define CSTRIDE 640     // padded col stride of HSoff
#define KSTEPS  80      // NF_/32
#define NBIG    40      // big-steps of BK=64
#define BM      128
#define BN      640
#define BSTEP_BYTES 40960   // BN*32*2 per K-step

typedef short bf16x8 __attribute__((ext_vector_type(8)));
typedef float f32x4  __attribute__((ext_vector_type(4)));

__device__ __forceinline__ unsigned f2bf(float f) {
    unsigned u = __builtin_bit_cast(unsigned, f);
    return (u + 0x7fffu + ((u >> 16) & 1u)) >> 16;   // RNE
}

// ---------------- kernel 1: fused {pack weights | energy head} ----------------
__global__ __launch_bounds__(512)
void prep_energy(const float* __restrict__ W_off, const float* __restrict__ W_ovoff,
                 const float* __restrict__ W_on, unsigned short* __restrict__ Bws,
                 const float* __restrict__ x, const float* __restrict__ W1,
                 const float* __restrict__ b1, const float* __restrict__ W2,
                 const float* __restrict__ b2, float* __restrict__ E) {
    const int t = threadIdx.x;
    if (blockIdx.x < KSTEPS) {
        __shared__ float wt[32 * BN];
        const int ks = blockIdx.x;
        for (int e = t; e < 32 * BN; e += 512) {
            int kl = e / BN, c = e - kl * BN;
            int kg = ks * 32 + kl;
            float v = 0.f;
            if (c < O2_)          v = W_off  [(size_t)kg * O2_ + c];
            else if (c < 2 * O2_) v = W_ovoff[(size_t)kg * O2_ + (c - O2_)];
            else if (c < 3 * O2_) v = W_on   [(size_t)kg * O2_ + (c - 2 * O2_)];
            wt[kl * BN + c] = v;
        }
        __syncthreads();
        unsigned short* out = Bws + (size_t)ks * (BN * 32);
        for (int e = t; e < BN * 4; e += 512) {
            int n = e >> 2, sg = e & 3;
            uint4 w;
            w.x = f2bf(wt[(sg * 8 + 0) * BN + n]) | (f2bf(wt[(sg * 8 + 1) * BN + n]) << 16);
            w.y = f2bf(wt[(sg * 8 + 2) * BN + n]) | (f2bf(wt[(sg * 8 + 3) * BN + n]) << 16);
            w.z = f2bf(wt[(sg * 8 + 4) * BN + n]) | (f2bf(wt[(sg * 8 + 5) * BN + n]) << 16);
            w.w = f2bf(wt[(sg * 8 + 6) * BN + n]) | (f2bf(wt[(sg * 8 + 7) * BN + n]) << 16);
            *(uint4*)(out + (size_t)n * 32 + sg * 8) = w;
        }
    } else {
        __shared__ float partial[8];
        const int b = blockIdx.x - KSTEPS;
        const int lane = t & 63;
        const int w = t >> 6;
        float esum = 0.f;
        for (int aa = 0; aa < 8; ++aa) {
            const int a = w * 8 + aa;
            const float* xr = x + (size_t)(b * A_ + a) * NC_;
            float hj = b1[lane];
            for (int k = 0; k < NC_; ++k) hj = fmaf(xr[k], W1[k * 64 + lane], hj);
            float sp = fmaxf(hj, 0.f) + log1pf(expf(-fabsf(hj))) - 0.69314718055994531f;
            float v = sp * W2[lane];
            for (int off = 32; off; off >>= 1) v += __shfl_down(v, off);
            if (lane == 0) esum += v + b2[0];
        }
        if (lane == 0) partial[w] = esum;
        __syncthreads();
        if (t == 0) {
            float e = 0.f;
            for (int k = 0; k < 8; ++k) e += partial[k];
            E[b] = e;
        }
    }
}

// ---------------- kernel 2: MFMA GEMM; BK=64 big-steps, deep A-stage, 10-slot B window ----------------
// 8 waves (2M x 4N), wave-tile 64x160, acc[4][10]; A LDS dbuf 2x16KB (XOR-swizzled); HBM-bound by design.
__global__ __launch_bounds__(512, 2)
void gemm_off(const float* __restrict__ V, const unsigned short* __restrict__ Bws,
              const float* __restrict__ b_off, const float* __restrict__ b_ovoff,
              const float* __restrict__ b_on, float* __restrict__ HSoff) {
    __shared__ alignas(16) unsigned short Alds[2][8192];  // [2 subtiles(k-step)][128 rows][32 k] bf16

    const int tid  = threadIdx.x;
    const int mt   = blockIdx.x;
    const int lane = tid & 63;
    const int wv   = tid >> 6;
    const int wm   = wv >> 2, wn = wv & 3;

    // staging map: thread -> (row, s): row = tid>>2 (128 rows), s = tid&3 covers k = s*16..s*16+15
    const int arow = tid >> 2, aseg = tid & 3;
    const float* aptr = V + (size_t)(mt * BM + arow) * NF_ + aseg * 16;

    const char* bp = (const char*)Bws + (size_t)(wn * 160 + (lane & 15)) * 64 + (lane >> 4) * 16;

    f32x4 acc[4][10];
#pragma unroll
    for (int mf = 0; mf < 4; ++mf)
#pragma unroll
        for (int nf = 0; nf < 10; ++nf)
            acc[mf][nf] = (f32x4){0.f, 0.f, 0.f, 0.f};

    float4 pv0, pv1, pv2, pv3;
    auto loadA = [&](const float* ap) {
        pv0 = ((const float4*)ap)[0];
        pv1 = ((const float4*)ap)[1];
        pv2 = ((const float4*)ap)[2];
        pv3 = ((const float4*)ap)[3];
    };
    // thread's 16 floats -> 2x16B into subtile (s>>1), half (s&1)
    auto writeA = [&](int bf) {
        uint4 w0, w1;
        w0.x = f2bf(pv0.x) | (f2bf(pv0.y) << 16);
        w0.y = f2bf(pv0.z) | (f2bf(pv0.w) << 16);
        w0.z = f2bf(pv1.x) | (f2bf(pv1.y) << 16);
        w0.w = f2bf(pv1.z) | (f2bf(pv1.w) << 16);
        w1.x = f2bf(pv2.x) | (f2bf(pv2.y) << 16);
        w1.y = f2bf(pv2.z) | (f2bf(pv2.w) << 16);
        w1.z = f2bf(pv3.x) | (f2bf(pv3.y) << 16);
        w1.w = f2bf(pv3.z) | (f2bf(pv3.w) << 16);
        char* base = (char*)&Alds[bf][0] + (aseg >> 1) * 8192;
        unsigned o0 = ((unsigned)(arow * 64 + (aseg & 1) * 32))      ^ ((unsigned)(arow & 7) << 4);
        unsigned o1 = ((unsigned)(arow * 64 + (aseg & 1) * 32 + 16)) ^ ((unsigned)(arow & 7) << 4);
        *(uint4*)(base + o0) = w0;
        *(uint4*)(base + o1) = w1;
    };

    const int ar = wm * 64 + (lane & 15);
    const unsigned kb = (unsigned)(lane >> 4) * 16;

#define ARD(ks2_, mf_) (*(const bf16x8*)(Ab + (ks2_) * 8192 + \
    ((((unsigned)((ar + (mf_) * 16) * 64) + kb)) ^ ((unsigned)((ar + (mf_) * 16) & 7) << 4))))

#define MFMA4(bv_, nf_) {                                                                  \
    acc[0][nf_] = __builtin_amdgcn_mfma_f32_16x16x32_bf16(af0, bv_, acc[0][nf_], 0, 0, 0); \
    acc[1][nf_] = __builtin_amdgcn_mfma_f32_16x16x32_bf16(af1, bv_, acc[1][nf_], 0, 0, 0); \
    acc[2][nf_] = __builtin_amdgcn_mfma_f32_16x16x32_bf16(af2, bv_, acc[2][nf_], 0, 0, 0); \
    acc[3][nf_] = __builtin_amdgcn_mfma_f32_16x16x32_bf16(af3, bv_, acc[3][nf_], 0, 0, 0); }

// consume bq (frag T) then reload same slot with frag T+1 (register WAR keeps the window shape)
#define CLUSTER(bq_, ks2_, nf_) { MFMA4(bq_, nf_); bq_ = *(const bf16x8*)(bpt + (ks2_) * BSTEP_BYTES + (nf_) * 1024); }

    bf16x8 bq0, bq1, bq2, bq3, bq4, bq5, bq6, bq7, bq8, bq9;

    // ---- prologue: stage big0 -> LDS buf0; issue big1; preload B window (step 0) ----
    loadA(aptr);
    writeA(0);                                   // compiler inserts precise vmcnt wait
    loadA(aptr + 64);                            // stage big1 (consumed end of bt=0)
    bq0 = *(const bf16x8*)(bp + 0 * 1024);
    bq1 = *(const bf16x8*)(bp + 1 * 1024);
    bq2 = *(const bf16x8*)(bp + 2 * 1024);
    bq3 = *(const bf16x8*)(bp + 3 * 1024);
    bq4 = *(const bf16x8*)(bp + 4 * 1024);
    bq5 = *(const bf16x8*)(bp + 5 * 1024);
    bq6 = *(const bf16x8*)(bp + 6 * 1024);
    bq7 = *(const bf16x8*)(bp + 7 * 1024);
    bq8 = *(const bf16x8*)(bp + 8 * 1024);
    bq9 = *(const bf16x8*)(bp + 9 * 1024);
    asm volatile("s_waitcnt lgkmcnt(0)" ::: "memory");
    __builtin_amdgcn_s_barrier();
    __builtin_amdgcn_sched_barrier(0);

    const float* apn = aptr + 2 * 64;            // next stage source (big2)
    const char*  bpt = bp + BSTEP_BYTES;         // reload source = step (bt*2 + ks2 + 1)

    int cur = 0;
    for (int bt = 0; bt < NBIG; ++bt) {
        const char* Ab = (const char*)&Alds[cur][0];
        bf16x8 af0, af1, af2, af3;

        // ---- k-step 0 of big-step ----
        af0 = ARD(0, 0); af1 = ARD(0, 1); af2 = ARD(0, 2); af3 = ARD(0, 3);
        CLUSTER(bq0, 0, 0); CLUSTER(bq1, 0, 1); CLUSTER(bq2, 0, 2); CLUSTER(bq3, 0, 3);
        CLUSTER(bq4, 0, 4); CLUSTER(bq5, 0, 5); CLUSTER(bq6, 0, 6); CLUSTER(bq7, 0, 7);
        CLUSTER(bq8, 0, 8); CLUSTER(bq9, 0, 9);
        // ---- k-step 1 ----
        af0 = ARD(1, 0); af1 = ARD(1, 1); af2 = ARD(1, 2); af3 = ARD(1, 3);
        CLUSTER(bq0, 1, 0); CLUSTER(bq1, 1, 1); CLUSTER(bq2, 1, 2); CLUSTER(bq3, 1, 3);
        CLUSTER(bq4, 1, 4); CLUSTER(bq5, 1, 5); CLUSTER(bq6, 1, 6); CLUSTER(bq7, 1, 7);
        CLUSTER(bq8, 1, 8); CLUSTER(bq9, 1, 9);
        bpt += 2 * BSTEP_BYTES;

        if (bt < NBIG - 1) {
            writeA(cur ^ 1);                     // stage regs (big bt+1) -> LDS; vmcnt by compiler
            if (bt < NBIG - 2) { loadA(apn); apn += 64; }   // issue big bt+2
            asm volatile("s_waitcnt lgkmcnt(0)" ::: "memory");
            __builtin_amdgcn_s_barrier();
            __builtin_amdgcn_sched_barrier(0);
            cur ^= 1;
        }
    }

    // ---- epilogue: C/D layout col=lane&15, row=(lane>>4)*4+reg ----
    const int c16 = lane & 15, rg = lane >> 4;
#pragma unroll
    for (int nf = 0; nf < 10; ++nf) {
        int C = wn * 160 + nf * 16 + c16;
        if (C >= NCOLS) continue;
        float bias = (C < O2_) ? b_off[C] : (C < 2 * O2_) ? b_ovoff[C - O2_] : b_on[C - 2 * O2_];
#pragma unroll
        for (int mf = 0; mf < 4; ++mf) {
            int R = mt * BM + wm * 64 + mf * 16 + rg * 4;
            float* o = HSoff + (size_t)R * CSTRIDE + C;
            o[0]           = acc[mf][nf][0] + bias;
            o[CSTRIDE]     = acc[mf][nf][1] + bias;
            o[2 * CSTRIDE] = acc[mf][nf][2] + bias;
            o[3 * CSTRIDE] = acc[mf][nf][3] + bias;
        }
    }
#undef ARD
#undef MFMA4
#undef CLUSTER
}

// ---------------- kernel 3: Hon = rowmean over 63 pair rows of cols [392,588) ----------------
__global__ void hon_reduce(const float* __restrict__ HSoff, float* __restrict__ Hon) {
    const int g = blockIdx.x;       // 0..511
    const int t = threadIdx.x;      // 256, t<196 active
    if (t >= O2_) return;
    const float* p0 = HSoff + (size_t)g * NPAIR * CSTRIDE + 2 * O2_ + t;
    const float* p1 = p0 + (size_t)21 * CSTRIDE;
    const float* p2 = p0 + (size_t)42 * CSTRIDE;
    float a0 = 0.f, a1 = 0.f, a2 = 0.f;
#pragma unroll 3
    for (int j = 0; j < 21; ++j) {
        a0 += p0[0]; a1 += p1[0]; a2 += p2[0];
        p0 += CSTRIDE; p1 += CSTRIDE; p2 += CSTRIDE;
    }
    Hon[(size_t)g * O2_ + t] = (a0 + a1 + a2) * (1.f / (float)NPAIR);
}

// ---------------- kernel 4: assemble H and S, LDS-staged, fully coalesced ----------------
__global__ __launch_bounds__(256)
void assemble_k(const float* __restrict__ HSoff, const float* __restrict__ Hon,
                const int* __restrict__ Z, const float* __restrict__ ov_emb,
                const float* __restrict__ orbE, const float* __restrict__ s0E,
                float* __restrict__ H, float* __restrict__ S) {
    __shared__ float Ai[NPAIR * 197];
    __shared__ float Bj[2][16 * 200];
    __shared__ float Dg[O2_];
    __shared__ float Dd[NORB_];

    const int bid = blockIdx.x;
    const int h = bid & 1, i = (bid >> 1) & 63, b = bid >> 7;
    const int t = threadIdx.x;
    const int g = b * A_ + i;
    const int z = Z[g];
    float* out = (h ? S : H) + (size_t)b * AO_ * AO_;

    const float* abase = HSoff + (size_t)g * NPAIR * CSTRIDE + h * O2_;
    for (int u = t; u < NPAIR * O2_; u += 256) {
        int jj = u / O2_, e = u - jj * O2_;
        Ai[jj * 197 + e] = abase[(size_t)jj * CSTRIDE + e];
    }
    if (t < O2_)   Dg[t] = h ? ov_emb[(size_t)z * O2_ + t]   : Hon[(size_t)g * O2_ + t];
    if (t < NORB_) Dd[t] = h ? s0E[(size_t)z * NORB_ + t]    : orbE[(size_t)z * NORB_ + t];

    auto stageB = [&](int buf, int jc) {
        for (int u = t; u < 16 * O2_; u += 256) {
            int jl = u / O2_, e = u - jl * O2_;
            int j = jc * 16 + jl;
            if (j != i) {
                int idx = (i < j) ? i : i - 1;
                Bj[buf][jl * 200 + e] =
                    HSoff[((size_t)(b * A_ + j) * NPAIR + idx) * CSTRIDE + h * O2_ + e];
            }
        }
    };
    stageB(0, 0);
    __syncthreads();

    const int tj = t / NORB_, tq = t - tj * NORB_;   // valid for t<224
    for (int jc = 0; jc < 4; ++jc) {
        if (jc < 3) stageB((jc + 1) & 1, jc + 1);
        if (t < 224) {
            const int j = jc * 16 + tj;
            const int cur = jc & 1;
#pragma unroll
            for (int p = 0; p < NORB_; ++p) {
                float v;
                if (j == i) {
                    v = 0.5f * (Dg[p * NORB_ + tq] + Dg[tq * NORB_ + p]);
                    if (p == tq) v += Dd[p];
                } else {
                    int jj = (j < i) ? j : j - 1;
                    v = 0.5f * (Ai[jj * 197 + p * NORB_ + tq] + Bj[cur][tj * 200 + tq * NORB_ + p]);
                }
                out[(size_t)(i * NORB_ + p) * AO_ + jc * 224 + t] = v;
            }
        }
        __syncthreads();
    }
}

// ---------------- launcher ----------------
extern "C" void kernel_launch(void* const* d_in, const int* in_sizes, int n_in,
                              void* d_out, int out_size, void* d_ws, size_t ws_size,
                              hipStream_t stream) {
    const int*   Z       = (const int*)  d_in[0];
    const float* x       = (const float*)d_in[2];
    const float* V       = (const float*)d_in[3];
    const float* W_off   = (const float*)d_in[4];
    const float* b_off   = (const float*)d_in[5];
    const float* W_on    = (const float*)d_in[6];
    const float* b_on    = (const float*)d_in[7];
    const float* W_ovoff = (const float*)d_in[8];
    const float* b_ovoff = (const float*)d_in[9];
    const float* ov_emb  = (const float*)d_in[10];
    const float* orbE    = (const float*)d_in[11];
    const float* s0E     = (const float*)d_in[12];
    const float* W1      = (const float*)d_in[13];
    const float* b1      = (const float*)d_in[14];
    const float* W2      = (const float*)d_in[15];
    const float* b2      = (const float*)d_in[16];

    float* H = (float*)d_out;
    float* S = H + (size_t)B_ * AO_ * AO_;
    float* E = S + (size_t)B_ * AO_ * AO_;

    char* ws = (char*)d_ws;
    unsigned short* Bws = (unsigned short*)ws;                     // 82 steps x 40960 B (80,81 = pad, never consumed)
    float* HSoff = (float*)(ws + (size_t)4  * 1024 * 1024);        // 82,575,360 B
    float* Hon   = (float*)(ws + (size_t)88 * 1024 * 1024);        //    401,408 B

    prep_energy<<<KSTEPS + B_, 512, 0, stream>>>(W_off, W_ovoff, W_on, Bws,
                                                 x, W1, b1, W2, b2, E);
    gemm_off   <<<252,  512, 0, stream>>>(V, Bws, b_off, b_ovoff, b_on, HSoff);
    hon_reduce <<<512,  256, 0, stream>>>(HSoff, Hon);
    assemble_k <<<1024, 256, 0, stream>>>(HSoff, Hon, Z, ov_emb, orbE, s0E, H, S);
}

// Round 8
// 265.880 us; speedup vs baseline: 1.3595x; 1.1604x over previous
//
#include <hip/hip_runtime.h>

// ---------------- problem constants ----------------
#define B_      8
#define A_      64
#define NPAIR   63
#define NC_     128
#define NF_     2560    // K
#define O2_     196     // 14*14
#define NORB_   14
#define AO_     896
#define NCOLS   588     // valid cols: [H_off 196 | S_off 196 | H_on 196]
#define CSTRIDE 640     // padded col stride of HSoff
#define KSTEPS  80      // NF_/32
#define BM      64
#define BN      640
#define BSTEP_BYTES 40960   // BN*32*2 per K-step

typedef short bf16x8 __attribute__((ext_vector_type(8)));
typedef float f32x4  __attribute__((ext_vector_type(4)));

__device__ __forceinline__ unsigned f2bf(float f) {
    unsigned u = __builtin_bit_cast(unsigned, f);
    return (u + 0x7fffu + ((u >> 16) & 1u)) >> 16;   // RNE
}

// ---------------- kernel 1: fused {pack weights | energy head} ----------------
// blocks 0..79: pack W -> bf16 [ks][n=640][k=32] LINEAR; blocks 80..87: energy.
__global__ __launch_bounds__(512)
void prep_energy(const float* __restrict__ W_off, const float* __restrict__ W_ovoff,
                 const float* __restrict__ W_on, unsigned short* __restrict__ Bws,
                 const float* __restrict__ x, const float* __restrict__ W1,
                 const float* __restrict__ b1, const float* __restrict__ W2,
                 const float* __restrict__ b2, float* __restrict__ E) {
    const int t = threadIdx.x;
    if (blockIdx.x < KSTEPS) {
        __shared__ float wt[32 * BN];
        const int ks = blockIdx.x;
        for (int e = t; e < 32 * BN; e += 512) {
            int kl = e / BN, c = e - kl * BN;
            int kg = ks * 32 + kl;
            float v = 0.f;
            if (c < O2_)          v = W_off  [(size_t)kg * O2_ + c];
            else if (c < 2 * O2_) v = W_ovoff[(size_t)kg * O2_ + (c - O2_)];
            else if (c < 3 * O2_) v = W_on   [(size_t)kg * O2_ + (c - 2 * O2_)];
            wt[kl * BN + c] = v;
        }
        __syncthreads();
        unsigned short* out = Bws + (size_t)ks * (BN * 32);
        for (int e = t; e < BN * 4; e += 512) {
            int n = e >> 2, sg = e & 3;
            uint4 w;
            w.x = f2bf(wt[(sg * 8 + 0) * BN + n]) | (f2bf(wt[(sg * 8 + 1) * BN + n]) << 16);
            w.y = f2bf(wt[(sg * 8 + 2) * BN + n]) | (f2bf(wt[(sg * 8 + 3) * BN + n]) << 16);
            w.z = f2bf(wt[(sg * 8 + 4) * BN + n]) | (f2bf(wt[(sg * 8 + 5) * BN + n]) << 16);
            w.w = f2bf(wt[(sg * 8 + 6) * BN + n]) | (f2bf(wt[(sg * 8 + 7) * BN + n]) << 16);
            *(uint4*)(out + (size_t)n * 32 + sg * 8) = w;
        }
    } else {
        __shared__ float partial[8];
        const int b = blockIdx.x - KSTEPS;
        const int lane = t & 63;
        const int w = t >> 6;
        float esum = 0.f;
        for (int aa = 0; aa < 8; ++aa) {
            const int a = w * 8 + aa;
            const float* xr = x + (size_t)(b * A_ + a) * NC_;
            float hj = b1[lane];
            for (int k = 0; k < NC_; ++k) hj = fmaf(xr[k], W1[k * 64 + lane], hj);
            float sp = fmaxf(hj, 0.f) + log1pf(expf(-fabsf(hj))) - 0.69314718055994531f;
            float v = sp * W2[lane];
            for (int off = 32; off; off >>= 1) v += __shfl_down(v, off);
            if (lane == 0) esum += v + b2[0];
        }
        if (lane == 0) partial[w] = esum;
        __syncthreads();
        if (t == 0) {
            float e = 0.f;
            for (int k = 0; k < 8; ++k) e += partial[k];
            E[b] = e;
        }
    }
}

// ---------------- kernel 2: MFMA GEMM; fp32-A via global_load_lds (src-swizzled), cvt-on-read ----------------
// BM=64, 8 waves each 64x80 (acc[4][5]=80 VGPR), 2 blocks/CU, counted vmcnt(5), 1 barrier/step.
__global__ __launch_bounds__(512, 4)
void gemm_off(const float* __restrict__ V, const unsigned short* __restrict__ Bws,
              const float* __restrict__ b_off, const float* __restrict__ b_ovoff,
              const float* __restrict__ b_on, float* __restrict__ HSoff) {
    __shared__ alignas(16) float Alds[2][BM * 32];   // 8 KB per buf, fp32, src-swizzled

    const int tid  = threadIdx.x;
    int mtb = blockIdx.x;
    mtb = (mtb & 7) * 63 + (mtb >> 3);               // XCD swizzle: 504 = 8 x 63 exactly
    const int mt   = mtb;
    const int lane = tid & 63;
    const int wv   = tid >> 6;                        // 0..7 = N-slice (wave tile 64x80)
    const int wvu  = __builtin_amdgcn_readfirstlane(wv);

    // A staging: thread tid covers chunk tid (16B): row r=tid>>3, stored-seg tid&7,
    // actual k-seg = (tid&7)^(r&7)  [source-side inverse of the read swizzle]
    const int rr  = tid >> 3;
    const int sgp = (tid & 7) ^ (rr & 7);
    const float* asrc = V + (size_t)(mt * BM + rr) * NF_ + sgp * 4;

    // B fragment base: frag(t, nf) at n = wv*80 + nf*16 + (lane&15), k-half (lane>>4)
    const char* bp = (const char*)Bws + (size_t)(wv * 80 + (lane & 15)) * 64 + (lane >> 4) * 16;
#define BFRAG(t_, nf_) (*(const bf16x8*)(bp + (size_t)(t_) * BSTEP_BYTES + (nf_) * 1024))

    f32x4 acc[4][5];
#pragma unroll
    for (int mf = 0; mf < 4; ++mf)
#pragma unroll
        for (int nf = 0; nf < 5; ++nf)
            acc[mf][nf] = (f32x4){0.f, 0.f, 0.f, 0.f};

    auto stage = [&](int buf, int t) {
        __builtin_amdgcn_global_load_lds(
            (const __attribute__((address_space(1))) void*)(asrc + (size_t)t * 32),
            (__attribute__((address_space(3))) void*)(&Alds[buf][wvu * 256]), 16, 0, 0);
    };

    const unsigned klo = (unsigned)(lane >> 4) * 2;   // even k-seg of this lane's 8-float slice

    union U8 { unsigned u[4]; bf16x8 v; };

    // read fp32 frag (2x ds_read_b128) + convert to bf16x8 via v_cvt_pk_bf16_f32 (RNE)
#define AFRAG(abf_, mf_, Abuf_) {                                                  \
    const unsigned R_ = (unsigned)(lane & 15) + (mf_) * 16;                        \
    const unsigned a0_ = R_ * 128 + ((klo ^ (R_ & 7)) << 4);                       \
    float4 lo_ = *(const float4*)((const char*)(Abuf_) + a0_);                     \
    float4 hi_ = *(const float4*)((const char*)(Abuf_) + (a0_ ^ 16));              \
    U8 uu_;                                                                        \
    asm("v_cvt_pk_bf16_f32 %0, %1, %2" : "=v"(uu_.u[0]) : "v"(lo_.x), "v"(lo_.y)); \
    asm("v_cvt_pk_bf16_f32 %0, %1, %2" : "=v"(uu_.u[1]) : "v"(lo_.z), "v"(lo_.w)); \
    asm("v_cvt_pk_bf16_f32 %0, %1, %2" : "=v"(uu_.u[2]) : "v"(hi_.x), "v"(hi_.y)); \
    asm("v_cvt_pk_bf16_f32 %0, %1, %2" : "=v"(uu_.u[3]) : "v"(hi_.z), "v"(hi_.w)); \
    abf_ = uu_.v; }

#define MFMA1(abf_, bq_, mf_, nf_) \
    acc[mf_][nf_] = __builtin_amdgcn_mfma_f32_16x16x32_bf16(abf_, bq_, acc[mf_][nf_], 0, 0, 0);

    bf16x8 bq0, bq1, bq2, bq3, bq4, abf;

    // ---- prologue: issue A-stage(0); preload B window(step 0) ----
    stage(0, 0);
    bq0 = BFRAG(0, 0); bq1 = BFRAG(0, 1); bq2 = BFRAG(0, 2); bq3 = BFRAG(0, 3); bq4 = BFRAG(0, 4);

    for (int t = 0; t < KSTEPS; ++t) {
        const int buf = t & 1;
        // counted wait: retire A-stage(t) (and older); keep the 5 newest B-loads in flight
        asm volatile("s_waitcnt vmcnt(5)" ::: "memory");
        __builtin_amdgcn_s_barrier();
        __builtin_amdgcn_sched_barrier(0);
        if (t + 1 < KSTEPS) stage(buf ^ 1, t + 1);

        const float* Abuf = &Alds[buf][0];
        AFRAG(abf, 0, Abuf);
        MFMA1(abf, bq0, 0, 0); MFMA1(abf, bq1, 0, 1); MFMA1(abf, bq2, 0, 2);
        MFMA1(abf, bq3, 0, 3); MFMA1(abf, bq4, 0, 4);
        AFRAG(abf, 1, Abuf);
        MFMA1(abf, bq0, 1, 0); MFMA1(abf, bq1, 1, 1); MFMA1(abf, bq2, 1, 2);
        MFMA1(abf, bq3, 1, 3); MFMA1(abf, bq4, 1, 4);
        AFRAG(abf, 2, Abuf);
        MFMA1(abf, bq0, 2, 0); MFMA1(abf, bq1, 2, 1); MFMA1(abf, bq2, 2, 2);
        MFMA1(abf, bq3, 2, 3); MFMA1(abf, bq4, 2, 4);
        AFRAG(abf, 3, Abuf);
        MFMA1(abf, bq0, 3, 0); bq0 = BFRAG(t + 1, 0);   // reload after last use (WAR pins order)
        MFMA1(abf, bq1, 3, 1); bq1 = BFRAG(t + 1, 1);   // t=79 reads pad step 80 (never consumed)
        MFMA1(abf, bq2, 3, 2); bq2 = BFRAG(t + 1, 2);
        MFMA1(abf, bq3, 3, 3); bq3 = BFRAG(t + 1, 3);
        MFMA1(abf, bq4, 3, 4); bq4 = BFRAG(t + 1, 4);
        __builtin_amdgcn_sched_barrier(0);
    }

    // ---- epilogue: C/D layout col=lane&15, row=(lane>>4)*4+reg ----
    const int c16 = lane & 15, rg = lane >> 4;
#pragma unroll
    for (int nf = 0; nf < 5; ++nf) {
        int C = wv * 80 + nf * 16 + c16;
        if (C >= NCOLS) continue;
        float bias = (C < O2_) ? b_off[C] : (C < 2 * O2_) ? b_ovoff[C - O2_] : b_on[C - 2 * O2_];
#pragma unroll
        for (int mf = 0; mf < 4; ++mf) {
            int R = mt * BM + mf * 16 + rg * 4;
            float* o = HSoff + (size_t)R * CSTRIDE + C;
            o[0]           = acc[mf][nf][0] + bias;
            o[CSTRIDE]     = acc[mf][nf][1] + bias;
            o[2 * CSTRIDE] = acc[mf][nf][2] + bias;
            o[3 * CSTRIDE] = acc[mf][nf][3] + bias;
        }
    }
#undef BFRAG
#undef AFRAG
#undef MFMA1
}

// ---------------- kernel 3: Hon = rowmean over 63 pair rows of cols [392,588) ----------------
__global__ void hon_reduce(const float* __restrict__ HSoff, float* __restrict__ Hon) {
    const int g = blockIdx.x;       // 0..511
    const int t = threadIdx.x;      // 256, t<196 active
    if (t >= O2_) return;
    const float* p0 = HSoff + (size_t)g * NPAIR * CSTRIDE + 2 * O2_ + t;
    const float* p1 = p0 + (size_t)21 * CSTRIDE;
    const float* p2 = p0 + (size_t)42 * CSTRIDE;
    float a0 = 0.f, a1 = 0.f, a2 = 0.f;
#pragma unroll 3
    for (int j = 0; j < 21; ++j) {
        a0 += p0[0]; a1 += p1[0]; a2 += p2[0];
        p0 += CSTRIDE; p1 += CSTRIDE; p2 += CSTRIDE;
    }
    Hon[(size_t)g * O2_ + t] = (a0 + a1 + a2) * (1.f / (float)NPAIR);
}

// ---------------- kernel 4: assemble H and S, LDS-staged, fully coalesced ----------------
__global__ __launch_bounds__(256)
void assemble_k(const float* __restrict__ HSoff, const float* __restrict__ Hon,
                const int* __restrict__ Z, const float* __restrict__ ov_emb,
                const float* __restrict__ orbE, const float* __restrict__ s0E,
                float* __restrict__ H, float* __restrict__ S) {
    __shared__ float Ai[NPAIR * 197];
    __shared__ float Bj[2][16 * 200];
    __shared__ float Dg[O2_];
    __shared__ float Dd[NORB_];

    const int bid = blockIdx.x;
    const int h = bid & 1, i = (bid >> 1) & 63, b = bid >> 7;
    const int t = threadIdx.x;
    const int g = b * A_ + i;
    const int z = Z[g];
    float* out = (h ? S : H) + (size_t)b * AO_ * AO_;

    const float* abase = HSoff + (size_t)g * NPAIR * CSTRIDE + h * O2_;
    for (int u = t; u < NPAIR * O2_; u += 256) {
        int jj = u / O2_, e = u - jj * O2_;
        Ai[jj * 197 + e] = abase[(size_t)jj * CSTRIDE + e];
    }
    if (t < O2_)   Dg[t] = h ? ov_emb[(size_t)z * O2_ + t]   : Hon[(size_t)g * O2_ + t];
    if (t < NORB_) Dd[t] = h ? s0E[(size_t)z * NORB_ + t]    : orbE[(size_t)z * NORB_ + t];

    auto stageB = [&](int buf, int jc) {
        for (int u = t; u < 16 * O2_; u += 256) {
            int jl = u / O2_, e = u - jl * O2_;
            int j = jc * 16 + jl;
            if (j != i) {
                int idx = (i < j) ? i : i - 1;
                Bj[buf][jl * 200 + e] =
                    HSoff[((size_t)(b * A_ + j) * NPAIR + idx) * CSTRIDE + h * O2_ + e];
            }
        }
    };
    stageB(0, 0);
    __syncthreads();

    const int tj = t / NORB_, tq = t - tj * NORB_;   // valid for t<224
    for (int jc = 0; jc < 4; ++jc) {
        if (jc < 3) stageB((jc + 1) & 1, jc + 1);
        if (t < 224) {
            const int j = jc * 16 + tj;
            const int cur = jc & 1;
#pragma unroll
            for (int p = 0; p < NORB_; ++p) {
                float v;
                if (j == i) {
                    v = 0.5f * (Dg[p * NORB_ + tq] + Dg[tq * NORB_ + p]);
                    if (p == tq) v += Dd[p];
                } else {
                    int jj = (j < i) ? j : j - 1;
                    v = 0.5f * (Ai[jj * 197 + p * NORB_ + tq] + Bj[cur][tj * 200 + tq * NORB_ + p]);
                }
                out[(size_t)(i * NORB_ + p) * AO_ + jc * 224 + t] = v;
            }
        }
        __syncthreads();
    }
}

// ---------------- launcher ----------------
extern "C" void kernel_launch(void* const* d_in, const int* in_sizes, int n_in,
                              void* d_out, int out_size, void* d_ws, size_t ws_size,
                              hipStream_t stream) {
    const int*   Z       = (const int*)  d_in[0];
    const float* x       = (const float*)d_in[2];
    const float* V       = (const float*)d_in[3];
    const float* W_off   = (const float*)d_in[4];
    const float* b_off   = (const float*)d_in[5];
    const float* W_on    = (const float*)d_in[6];
    const float* b_on    = (const float*)d_in[7];
    const float* W_ovoff = (const float*)d_in[8];
    const float* b_ovoff = (const float*)d_in[9];
    const float* ov_emb  = (const float*)d_in[10];
    const float* orbE    = (const float*)d_in[11];
    const float* s0E     = (const float*)d_in[12];
    const float* W1      = (const float*)d_in[13];
    const float* b1      = (const float*)d_in[14];
    const float* W2      = (const float*)d_in[15];
    const float* b2      = (const float*)d_in[16];

    float* H = (float*)d_out;
    float* S = H + (size_t)B_ * AO_ * AO_;
    float* E = S + (size_t)B_ * AO_ * AO_;

    char* ws = (char*)d_ws;
    unsigned short* Bws = (unsigned short*)ws;                     // 81 steps x 40960 B (step 80 = pad)
    float* HSoff = (float*)(ws + (size_t)4  * 1024 * 1024);        // 82,575,360 B
    float* Hon   = (float*)(ws + (size_t)88 * 1024 * 1024);        //    401,408 B

    prep_energy<<<KSTEPS + B_, 512, 0, stream>>>(W_off, W_ovoff, W_on, Bws,
                                                 x, W1, b1, W2, b2, E);
    gemm_off   <<<504,  512, 0, stream>>>(V, Bws, b_off, b_ovoff, b_on, HSoff);
    hon_reduce <<<512,  256, 0, stream>>>(HSoff, Hon);
    assemble_k <<<1024, 256, 0, stream>>>(HSoff, Hon, Z, ov_emb, orbE, s0E, H, S);
}

// Round 9
// 263.686 us; speedup vs baseline: 1.3709x; 1.0083x over previous
//
#include <hip/hip_runtime.h>

// ---------------- problem constants ----------------
#define B_      8
#define A_      64
#define NPAIR   63
#define NC_     128
#define NF_     2560    // K
#define O2_     196     // 14*14
#define NORB_   14
#define AO_     896
#define NCOLS   588     // valid cols: [H_off 196 | S_off 196 | H_on 196]
#define CSTRIDE 640     // padded col stride of HSoff
#define KSTEPS  80      // NF_/32
#define BM      64
#define BN      640
#define BSTEP_BYTES 40960   // BN*32*2 per K-step

typedef short bf16x8 __attribute__((ext_vector_type(8)));
typedef float f32x4  __attribute__((ext_vector_type(4)));

__device__ __forceinline__ unsigned f2bf(float f) {
    unsigned u = __builtin_bit_cast(unsigned, f);
    return (u + 0x7fffu + ((u >> 16) & 1u)) >> 16;   // RNE
}

// ---------------- kernel 1: fused {pack weights | energy head} ----------------
__global__ __launch_bounds__(512)
void prep_energy(const float* __restrict__ W_off, const float* __restrict__ W_ovoff,
                 const float* __restrict__ W_on, unsigned short* __restrict__ Bws,
                 const float* __restrict__ x, const float* __restrict__ W1,
                 const float* __restrict__ b1, const float* __restrict__ W2,
                 const float* __restrict__ b2, float* __restrict__ E) {
    const int t = threadIdx.x;
    if (blockIdx.x < KSTEPS) {
        __shared__ float wt[32 * BN];
        const int ks = blockIdx.x;
        for (int e = t; e < 32 * BN; e += 512) {
            int kl = e / BN, c = e - kl * BN;
            int kg = ks * 32 + kl;
            float v = 0.f;
            if (c < O2_)          v = W_off  [(size_t)kg * O2_ + c];
            else if (c < 2 * O2_) v = W_ovoff[(size_t)kg * O2_ + (c - O2_)];
            else if (c < 3 * O2_) v = W_on   [(size_t)kg * O2_ + (c - 2 * O2_)];
            wt[kl * BN + c] = v;
        }
        __syncthreads();
        unsigned short* out = Bws + (size_t)ks * (BN * 32);
        for (int e = t; e < BN * 4; e += 512) {
            int n = e >> 2, sg = e & 3;
            uint4 w;
            w.x = f2bf(wt[(sg * 8 + 0) * BN + n]) | (f2bf(wt[(sg * 8 + 1) * BN + n]) << 16);
            w.y = f2bf(wt[(sg * 8 + 2) * BN + n]) | (f2bf(wt[(sg * 8 + 3) * BN + n]) << 16);
            w.z = f2bf(wt[(sg * 8 + 4) * BN + n]) | (f2bf(wt[(sg * 8 + 5) * BN + n]) << 16);
            w.w = f2bf(wt[(sg * 8 + 6) * BN + n]) | (f2bf(wt[(sg * 8 + 7) * BN + n]) << 16);
            *(uint4*)(out + (size_t)n * 32 + sg * 8) = w;
        }
    } else {
        __shared__ float partial[8];
        const int b = blockIdx.x - KSTEPS;
        const int lane = t & 63;
        const int w = t >> 6;
        float esum = 0.f;
        for (int aa = 0; aa < 8; ++aa) {
            const int a = w * 8 + aa;
            const float* xr = x + (size_t)(b * A_ + a) * NC_;
            float hj = b1[lane];
            for (int k = 0; k < NC_; ++k) hj = fmaf(xr[k], W1[k * 64 + lane], hj);
            float sp = fmaxf(hj, 0.f) + log1pf(expf(-fabsf(hj))) - 0.69314718055994531f;
            float v = sp * W2[lane];
            for (int off = 32; off; off >>= 1) v += __shfl_down(v, off);
            if (lane == 0) esum += v + b2[0];
        }
        if (lane == 0) partial[w] = esum;
        __syncthreads();
        if (t == 0) {
            float e = 0.f;
            for (int k = 0; k < 8; ++k) e += partial[k];
            E[b] = e;
        }
    }
}

// ---------------- kernel 2: MFMA GEMM; linear fp32 A-stage -> conv pass -> bf16 swizzled tile ----------------
// BM=64, 8 waves 1Mx8N (wave 64x80, acc[4][5]), 2 blocks/CU, counted vmcnt(5), 2 barriers/step.
__global__ __launch_bounds__(512, 4)
void gemm_off(const float* __restrict__ V, const unsigned short* __restrict__ Bws,
              const float* __restrict__ b_off, const float* __restrict__ b_ovoff,
              const float* __restrict__ b_on, float* __restrict__ HSoff) {
    __shared__ alignas(16) float          Af32[2][BM * 32];        // 2 x 8 KB, linear
    __shared__ alignas(16) unsigned short Ab16[2][BM * 32];        // 2 x 4 KB, slot-swizzled

    const int tid  = threadIdx.x;
    int mtb = blockIdx.x;
    mtb = (mtb & 7) * 63 + (mtb >> 3);               // XCD swizzle: 504 = 8 x 63 bijective
    const int mt   = mtb;
    const int lane = tid & 63;
    const int wv   = tid >> 6;                        // 0..7 = N-slice (wave tile 64x80)
    const int wvu  = __builtin_amdgcn_readfirstlane(wv);

    // linear fp32 stage: chunk tid (16B) = row rr=tid>>3, float-seg tid&7 (coalesced 128B/row)
    const float* asrc = V + (size_t)(mt * BM + (tid >> 3)) * NF_ + (tid & 7) * 4;

    // B fragment base: frag(t, nf) at n = wv*80 + nf*16 + (lane&15), k-half (lane>>4)
    const char* bp = (const char*)Bws + (size_t)(wv * 80 + (lane & 15)) * 64 + (lane >> 4) * 16;
#define BFRAG(t_, nf_) (*(const bf16x8*)(bp + (size_t)(t_) * BSTEP_BYTES + (nf_) * 1024))

    f32x4 acc[4][5];
#pragma unroll
    for (int mf = 0; mf < 4; ++mf)
#pragma unroll
        for (int nf = 0; nf < 5; ++nf)
            acc[mf][nf] = (f32x4){0.f, 0.f, 0.f, 0.f};

    auto stage = [&](int buf, int t) {
        __builtin_amdgcn_global_load_lds(
            (const __attribute__((address_space(1))) void*)(asrc + (size_t)t * 32),
            (__attribute__((address_space(3))) void*)(&Af32[buf][wvu * 256]), 16, 0, 0);
    };

    // conv: thread's 16B fp32 -> 8B bf16 at swizzled slot. slot(R) perm covers 32 banks exactly 2x.
    const int crr = tid >> 3, cq = tid & 7;
    const int csl = ((cq >> 1) + ((crr + (crr >> 2)) & 3)) & 3;
    char* const cdst_base0 = (char*)&Ab16[0][0] + crr * 64 + csl * 16 + (cq & 1) * 8;
    char* const cdst_base1 = (char*)&Ab16[1][0] + crr * 64 + csl * 16 + (cq & 1) * 8;

    const unsigned klo4 = (unsigned)(lane >> 4);

#define AFRAG(abf_, mf_, Bb16_) {                                                   \
    const unsigned R_ = (unsigned)(lane & 15) + (mf_) * 16;                         \
    const unsigned sl_ = (klo4 + ((R_ + (R_ >> 2)) & 3)) & 3;                       \
    abf_ = *(const bf16x8*)((const char*)(Bb16_) + R_ * 64 + sl_ * 16); }

#define MFMA1(abf_, bq_, mf_, nf_) \
    acc[mf_][nf_] = __builtin_amdgcn_mfma_f32_16x16x32_bf16(abf_, bq_, acc[mf_][nf_], 0, 0, 0);

    bf16x8 bq0, bq1, bq2, bq3, bq4, abf;

    // ---- prologue: issue A-stage(0); preload B window(step 0) ----
    stage(0, 0);
    bq0 = BFRAG(0, 0); bq1 = BFRAG(0, 1); bq2 = BFRAG(0, 2); bq3 = BFRAG(0, 3); bq4 = BFRAG(0, 4);

    for (int t = 0; t < KSTEPS; ++t) {
        const int buf = t & 1;
        // retire A-stage(t) (oldest); keep the 5 newest B-loads in flight
        asm volatile("s_waitcnt vmcnt(5)" ::: "memory");
        __builtin_amdgcn_sched_barrier(0);
        __builtin_amdgcn_s_barrier();                 // b1: Af32[buf] fully written
        __builtin_amdgcn_sched_barrier(0);
        if (t + 1 < KSTEPS) stage(buf ^ 1, t + 1);

        // conv phase: Af32[buf] -> Ab16[buf]
        {
            float4 cf = *(const float4*)((const char*)&Af32[buf][0] + tid * 16);
            unsigned lo, hi;
            asm("v_cvt_pk_bf16_f32 %0, %1, %2" : "=v"(lo) : "v"(cf.x), "v"(cf.y));
            asm("v_cvt_pk_bf16_f32 %0, %1, %2" : "=v"(hi) : "v"(cf.z), "v"(cf.w));
            uint2 cw = {lo, hi};
            *(uint2*)(buf ? cdst_base1 : cdst_base0) = cw;
        }
        asm volatile("s_waitcnt lgkmcnt(0)" ::: "memory");
        __builtin_amdgcn_sched_barrier(0);
        __builtin_amdgcn_s_barrier();                 // b2: Ab16[buf] ready
        __builtin_amdgcn_sched_barrier(0);

        const unsigned short* At = &Ab16[buf][0];
        AFRAG(abf, 0, At);
        __builtin_amdgcn_s_setprio(1);
        MFMA1(abf, bq0, 0, 0); MFMA1(abf, bq1, 0, 1); MFMA1(abf, bq2, 0, 2);
        MFMA1(abf, bq3, 0, 3); MFMA1(abf, bq4, 0, 4);
        __builtin_amdgcn_s_setprio(0);
        AFRAG(abf, 1, At);
        __builtin_amdgcn_s_setprio(1);
        MFMA1(abf, bq0, 1, 0); MFMA1(abf, bq1, 1, 1); MFMA1(abf, bq2, 1, 2);
        MFMA1(abf, bq3, 1, 3); MFMA1(abf, bq4, 1, 4);
        __builtin_amdgcn_s_setprio(0);
        AFRAG(abf, 2, At);
        __builtin_amdgcn_s_setprio(1);
        MFMA1(abf, bq0, 2, 0); MFMA1(abf, bq1, 2, 1); MFMA1(abf, bq2, 2, 2);
        MFMA1(abf, bq3, 2, 3); MFMA1(abf, bq4, 2, 4);
        __builtin_amdgcn_s_setprio(0);
        AFRAG(abf, 3, At);
        __builtin_amdgcn_s_setprio(1);
        MFMA1(abf, bq0, 3, 0); bq0 = BFRAG(t + 1, 0);   // reload after last use; t=79 reads pad step 80
        MFMA1(abf, bq1, 3, 1); bq1 = BFRAG(t + 1, 1);
        MFMA1(abf, bq2, 3, 2); bq2 = BFRAG(t + 1, 2);
        MFMA1(abf, bq3, 3, 3); bq3 = BFRAG(t + 1, 3);
        MFMA1(abf, bq4, 3, 4); bq4 = BFRAG(t + 1, 4);
        __builtin_amdgcn_s_setprio(0);
        __builtin_amdgcn_sched_barrier(0);
    }

    // ---- epilogue: C/D layout col=lane&15, row=(lane>>4)*4+reg ----
    const int c16 = lane & 15, rg = lane >> 4;
#pragma unroll
    for (int nf = 0; nf < 5; ++nf) {
        int C = wv * 80 + nf * 16 + c16;
        if (C >= NCOLS) continue;
        float bias = (C < O2_) ? b_off[C] : (C < 2 * O2_) ? b_ovoff[C - O2_] : b_on[C - 2 * O2_];
#pragma unroll
        for (int mf = 0; mf < 4; ++mf) {
            int R = mt * BM + mf * 16 + rg * 4;
            float* o = HSoff + (size_t)R * CSTRIDE + C;
            o[0]           = acc[mf][nf][0] + bias;
            o[CSTRIDE]     = acc[mf][nf][1] + bias;
            o[2 * CSTRIDE] = acc[mf][nf][2] + bias;
            o[3 * CSTRIDE] = acc[mf][nf][3] + bias;
        }
    }
#undef BFRAG
#undef AFRAG
#undef MFMA1
}

// ---------------- kernel 3: Hon = rowmean over 63 pair rows of cols [392,588) ----------------
__global__ void hon_reduce(const float* __restrict__ HSoff, float* __restrict__ Hon) {
    const int g = blockIdx.x;       // 0..511
    const int t = threadIdx.x;      // 256, t<196 active
    if (t >= O2_) return;
    const float* p0 = HSoff + (size_t)g * NPAIR * CSTRIDE + 2 * O2_ + t;
    const float* p1 = p0 + (size_t)21 * CSTRIDE;
    const float* p2 = p0 + (size_t)42 * CSTRIDE;
    float a0 = 0.f, a1 = 0.f, a2 = 0.f;
#pragma unroll 3
    for (int j = 0; j < 21; ++j) {
        a0 += p0[0]; a1 += p1[0]; a2 += p2[0];
        p0 += CSTRIDE; p1 += CSTRIDE; p2 += CSTRIDE;
    }
    Hon[(size_t)g * O2_ + t] = (a0 + a1 + a2) * (1.f / (float)NPAIR);
}

// ---------------- kernel 4: assemble H and S, LDS-staged, fully coalesced ----------------
__global__ __launch_bounds__(256)
void assemble_k(const float* __restrict__ HSoff, const float* __restrict__ Hon,
                const int* __restrict__ Z, const float* __restrict__ ov_emb,
                const float* __restrict__ orbE, const float* __restrict__ s0E,
                float* __restrict__ H, float* __restrict__ S) {
    __shared__ float Ai[NPAIR * 197];
    __shared__ float Bj[2][16 * 200];
    __shared__ float Dg[O2_];
    __shared__ float Dd[NORB_];

    const int bid = blockIdx.x;
    const int h = bid & 1, i = (bid >> 1) & 63, b = bid >> 7;
    const int t = threadIdx.x;
    const int g = b * A_ + i;
    const int z = Z[g];
    float* out = (h ? S : H) + (size_t)b * AO_ * AO_;

    const float* abase = HSoff + (size_t)g * NPAIR * CSTRIDE + h * O2_;
    for (int u = t; u < NPAIR * O2_; u += 256) {
        int jj = u / O2_, e = u - jj * O2_;
        Ai[jj * 197 + e] = abase[(size_t)jj * CSTRIDE + e];
    }
    if (t < O2_)   Dg[t] = h ? ov_emb[(size_t)z * O2_ + t]   : Hon[(size_t)g * O2_ + t];
    if (t < NORB_) Dd[t] = h ? s0E[(size_t)z * NORB_ + t]    : orbE[(size_t)z * NORB_ + t];

    auto stageB = [&](int buf, int jc) {
        for (int u = t; u < 16 * O2_; u += 256) {
            int jl = u / O2_, e = u - jl * O2_;
            int j = jc * 16 + jl;
            if (j != i) {
                int idx = (i < j) ? i : i - 1;
                Bj[buf][jl * 200 + e] =
                    HSoff[((size_t)(b * A_ + j) * NPAIR + idx) * CSTRIDE + h * O2_ + e];
            }
        }
    };
    stageB(0, 0);
    __syncthreads();

    const int tj = t / NORB_, tq = t - tj * NORB_;   // valid for t<224
    for (int jc = 0; jc < 4; ++jc) {
        if (jc < 3) stageB((jc + 1) & 1, jc + 1);
        if (t < 224) {
            const int j = jc * 16 + tj;
            const int cur = jc & 1;
#pragma unroll
            for (int p = 0; p < NORB_; ++p) {
                float v;
                if (j == i) {
                    v = 0.5f * (Dg[p * NORB_ + tq] + Dg[tq * NORB_ + p]);
                    if (p == tq) v += Dd[p];
                } else {
                    int jj = (j < i) ? j : j - 1;
                    v = 0.5f * (Ai[jj * 197 + p * NORB_ + tq] + Bj[cur][tj * 200 + tq * NORB_ + p]);
                }
                out[(size_t)(i * NORB_ + p) * AO_ + jc * 224 + t] = v;
            }
        }
        __syncthreads();
    }
}

// ---------------- launcher ----------------
extern "C" void kernel_launch(void* const* d_in, const int* in_sizes, int n_in,
                              void* d_out, int out_size, void* d_ws, size_t ws_size,
                              hipStream_t stream) {
    const int*   Z       = (const int*)  d_in[0];
    const float* x       = (const float*)d_in[2];
    const float* V       = (const float*)d_in[3];
    const float* W_off   = (const float*)d_in[4];
    const float* b_off   = (const float*)d_in[5];
    const float* W_on    = (const float*)d_in[6];
    const float* b_on    = (const float*)d_in[7];
    const float* W_ovoff = (const float*)d_in[8];
    const float* b_ovoff = (const float*)d_in[9];
    const float* ov_emb  = (const float*)d_in[10];
    const float* orbE    = (const float*)d_in[11];
    const float* s0E     = (const float*)d_in[12];
    const float* W1      = (const float*)d_in[13];
    const float* b1      = (const float*)d_in[14];
    const float* W2      = (const float*)d_in[15];
    const float* b2      = (const float*)d_in[16];

    float* H = (float*)d_out;
    float* S = H + (size_t)B_ * AO_ * AO_;
    float* E = S + (size_t)B_ * AO_ * AO_;

    char* ws = (char*)d_ws;
    unsigned short* Bws = (unsigned short*)ws;                     // 81 steps x 40960 B (step 80 = pad)
    float* HSoff = (float*)(ws + (size_t)4  * 1024 * 1024);        // 82,575,360 B
    float* Hon   = (float*)(ws + (size_t)88 * 1024 * 1024);        //    401,408 B

    prep_energy<<<KSTEPS + B_, 512, 0, stream>>>(W_off, W_ovoff, W_on, Bws,
                                                 x, W1, b1, W2, b2, E);
    gemm_off   <<<504,  512, 0, stream>>>(V, Bws, b_off, b_ovoff, b_on, HSoff);
    hon_reduce <<<512,  256, 0, stream>>>(HSoff, Hon);
    assemble_k <<<1024, 256, 0, stream>>>(HSoff, Hon, Z, ov_emb, orbE, s0E, H, S);
}